// Round 2
// baseline (229.587 us; speedup 1.0000x reference)
//
#include <hip/hip_runtime.h>

// Blur = UpFirDn2D(up=2, dn=2, k=4x4 outer([1,3,3,1])/16) collapses to a
// 2x2 stencil (only odd taps hit non-zero interleaved samples):
//   out[i][j] = F[1][1]*x[i][j] + F[1][3]*x[i][j+1]
//             + F[3][1]*x[i+1][j] + F[3][3]*x[i+1][j+1],  OOB x = 0.
// Memory-bound: 268 MB unique traffic -> ~43-49 us floor at 5.5-6.3 TB/s.
//
// R1: neighbor (j+4) taps via __shfl_down(lane+1); weights scalarized via
//     readfirstlane (channel wave-uniform). VMEM/thread 9 -> 3.
// R2: two output rows per thread (read amplification 2.0x -> 1.5x) + nt
//     loads/stores. NEUTRAL vs R1.
// R3 (this round): keep row-pairing, REMOVE all nontemporal hints.
//     Single-variable test: harness fills hit 6.5 TB/s with normal cached
//     writes; if nt stores were breaking write-combining, this recovers
//     ~10 us. If neutral again, blur is at the mixed-stream floor and the
//     rest of dur_us is harness poison fills -> roofline.

constexpr int NB = 8, NC = 256, H = 128, W = 128;

typedef float f4v __attribute__((ext_vector_type(4)));

__global__ __launch_bounds__(256) void blur_kernel(
    const float* __restrict__ x,
    const float* __restrict__ filt,
    float* __restrict__ out)
{
    int t = blockIdx.x * blockDim.x + threadIdx.x;
    // threads = NB*NC * (H/2) * (W/4) = 4194304
    int q   = t & 31;          // float4 index within row (j = 4*q)
    int rp  = (t >> 5) & 63;   // row-pair index: output rows 2rp, 2rp+1
    int img = t >> 11;         // b*NC + c (wave-uniform: 2048 threads/img)
    int c   = img & (NC - 1);

    // channel is wave-uniform -> force SGPR address -> s_load for weights
    int cu = __builtin_amdgcn_readfirstlane(c);
    const float* fb = filt + cu * 16;
    float w11 = fb[5], w13 = fb[7], w31 = fb[13], w33 = fb[15];

    int r0 = rp << 1;
    const float* row0 = x + ((size_t)img * H + r0) * W + (q << 2);

    f4v a = *(const f4v*)row0;            // row r0
    f4v b = *(const f4v*)(row0 + W);      // row r0+1
    f4v cc = {0.f, 0.f, 0.f, 0.f};
    if (rp < 63) cc = *(const f4v*)(row0 + 2 * W);  // row r0+2 (reused by next rp)

    // j+4 neighbor elements from the next lane (same row for q<31;
    // lanes 0-31 hold row-pair rp, lanes 32-63 hold rp+1, so lane+1 is the
    // next float4 of the same row except at q==31).
    float aR = __shfl_down(a.x, 1);
    float bR = __shfl_down(b.x, 1);
    float cR = __shfl_down(cc.x, 1);
    if (q == 31) { aR = 0.0f; bR = 0.0f; cR = 0.0f; }

    f4v o0, o1;
    o0.x = w11 * a.x + w13 * a.y + w31 * b.x + w33 * b.y;
    o0.y = w11 * a.y + w13 * a.z + w31 * b.y + w33 * b.z;
    o0.z = w11 * a.z + w13 * a.w + w31 * b.z + w33 * b.w;
    o0.w = w11 * a.w + w13 * aR  + w31 * b.w + w33 * bR;

    o1.x = w11 * b.x + w13 * b.y + w31 * cc.x + w33 * cc.y;
    o1.y = w11 * b.y + w13 * b.z + w31 * cc.y + w33 * cc.z;
    o1.z = w11 * b.z + w13 * b.w + w31 * cc.z + w33 * cc.w;
    o1.w = w11 * b.w + w13 * bR  + w31 * cc.w + w33 * cR;

    float* op = out + ((size_t)img * H + r0) * W + (q << 2);
    *(f4v*)op       = o0;
    *(f4v*)(op + W) = o1;
}

extern "C" void kernel_launch(void* const* d_in, const int* in_sizes, int n_in,
                              void* d_out, int out_size, void* d_ws, size_t ws_size,
                              hipStream_t stream)
{
    const float* x    = (const float*)d_in[0];
    const float* filt = (const float*)d_in[1];
    float* out        = (float*)d_out;

    const int total = NB * NC * (H / 2) * (W / 4);  // 4194304
    const int block = 256;
    const int grid  = total / block;                // 16384

    blur_kernel<<<grid, block, 0, stream>>>(x, filt, out);
}

// Round 3
// 223.226 us; speedup vs baseline: 1.0285x; 1.0285x over previous
//
#include <hip/hip_runtime.h>

// Blur = UpFirDn2D(up=2, dn=2, k=4x4 outer([1,3,3,1])/16) collapses to a
// 2x2 stencil (only odd taps hit non-zero interleaved samples):
//   out[i][j] = F[1][1]*x[i][j] + F[1][3]*x[i][j+1]
//             + F[3][1]*x[i+1][j] + F[3][3]*x[i+1][j+1],  OOB x = 0.
// Memory-bound: ~268 MB traffic -> ~43 us floor at 6.3 TB/s.
//
// R1: minimize VMEM issue. Neighbor (j+4) taps come from lane+1 via shuffle
// (lanes 0..31 = row r, lanes 32..63 = row r+1, so lane+1 holds the next
// float4 of the same row; q==31 masked to 0). Weight loads scalarized via
// readfirstlane (channel is wave-uniform). VMEM/thread: 9 -> 3.
// R2 (2-row/thread + nt, 224.5us) and R3 (2-row plain, 229.6us) were both
// neutral-to-worse: blur is at its memory floor; timed region is dominated
// by two ~81us harness poison fills. R4: revert to best-measured variant.

constexpr int NB = 8, NC = 256, H = 128, W = 128;

__global__ __launch_bounds__(256) void blur_kernel(
    const float* __restrict__ x,
    const float* __restrict__ filt,
    float* __restrict__ out)
{
    int t = blockIdx.x * blockDim.x + threadIdx.x;
    // total float4s = (NB*NC) * H * (W/4) = 8388608
    int q   = t & 31;          // float4 index within row (j = 4*q)
    int r   = (t >> 5) & 127;  // row (lanes 0-31: even r, lanes 32-63: r+1)
    int img = t >> 12;         // b*NC + c  (wave-uniform: 4096 threads/img)
    int c   = img & (NC - 1);

    // channel is wave-uniform -> force SGPR address -> s_load for weights
    int cu = __builtin_amdgcn_readfirstlane(c);
    const float* fb = filt + cu * 16;
    float w11 = fb[5], w13 = fb[7], w31 = fb[13], w33 = fb[15];

    const float* row0 = x + ((size_t)img * H + r) * W + (q << 2);
    float4 a = *(const float4*)row0;

    float4 b = make_float4(0.f, 0.f, 0.f, 0.f);
    if (r < H - 1) b = *(const float4*)(row0 + W);

    // j+4 neighbor elements from the next lane (same row for q<31)
    float aR = __shfl_down(a.x, 1);
    float bR = __shfl_down(b.x, 1);
    if (q == 31) { aR = 0.0f; bR = 0.0f; }

    float4 o;
    o.x = w11 * a.x + w13 * a.y + w31 * b.x + w33 * b.y;
    o.y = w11 * a.y + w13 * a.z + w31 * b.y + w33 * b.z;
    o.z = w11 * a.z + w13 * a.w + w31 * b.z + w33 * b.w;
    o.w = w11 * a.w + w13 * aR  + w31 * b.w + w33 * bR;

    *(float4*)(out + ((size_t)img * H + r) * W + (q << 2)) = o;
}

extern "C" void kernel_launch(void* const* d_in, const int* in_sizes, int n_in,
                              void* d_out, int out_size, void* d_ws, size_t ws_size,
                              hipStream_t stream)
{
    const float* x    = (const float*)d_in[0];
    const float* filt = (const float*)d_in[1];
    float* out        = (float*)d_out;

    const int total_f4 = NB * NC * H * (W / 4);   // 8388608
    const int block = 256;
    const int grid  = total_f4 / block;           // 32768

    blur_kernel<<<grid, block, 0, stream>>>(x, filt, out);
}